// Round 1
// 394.685 us; speedup vs baseline: 1.0440x; 1.0440x over previous
//
#include <hip/hip_runtime.h>
#include <math.h>

#define N_ROWS 65536
#define D 256
#define K 2048

// d_out float layout: z_q_st | loss | indices | perplexity
#define LOSS_OFF 16777216L
#define IDX_OFF  16777217L
#define PERP_OFF 16842753L

// ws byte layout
#define WS_HIST    0           // 2048*4
#define WS_LOSS    8192
#define WS_FLAGCNT 8196
#define WS_ENORM   8448        // 2048*4 (exact fp32, rescue)
#define WS_ENORM64 16640       // 2048*4 (64*enorm, argmin epilogue)
#define WS_FLAGS   24832       // 65536*4
#define WS_BPK     287232      // 1 MB frag-packed B

#define FLAG_Q 12              // quantized-gap threshold (12/64 = 0.1875)

typedef _Float16 half8 __attribute__((ext_vector_type(8)));
typedef float floatx4 __attribute__((ext_vector_type(4)));

// ---- convert B: ew fp32 -> fp16 frag-packed bpk + enorm/enorm64 + zero accumulators
__global__ __launch_bounds__(256) void convertB_kernel(const float* __restrict__ ew,
                                                       char* __restrict__ bpk,
                                                       float* __restrict__ enorm,
                                                       float* __restrict__ enorm64,
                                                       int* __restrict__ hist,
                                                       float* __restrict__ loss_acc,
                                                       int* __restrict__ flagcnt) {
  const int gid = blockIdx.x * 256 + threadIdx.x;   // 16384
  if (gid < 2048) hist[gid] = 0;
  else if (gid == 2048) *loss_acc = 0.f;
  else if (gid == 2049) *flagcnt = 0;

  const int code = gid >> 3, kc = gid & 7;
  const float4* s4 = (const float4*)(ew + (size_t)code * D + kc * 32);
  float buf[32];
#pragma unroll
  for (int q = 0; q < 8; ++q) *(float4*)&buf[q * 4] = s4[q];
  float s = 0.f;
#pragma unroll
  for (int k = 0; k < 32; ++k) s = fmaf(buf[k], buf[k], s);
  s += __shfl_xor(s, 1, 64); s += __shfl_xor(s, 2, 64); s += __shfl_xor(s, 4, 64);
  if (kc == 0) { enorm[code] = s; enorm64[code] = s * 64.0f; }
  _Float16 hi[32];
#pragma unroll
  for (int k = 0; k < 32; ++k) hi[k] = (_Float16)buf[k];
  // chunk = (code>>4)*8 + kc ; within chunk lane = (code&15) + 16*q holds halfs q*8..q*8+7
  char* base = bpk + (((size_t)(code >> 4) * 8 + kc) << 10) + (code & 15) * 16;
#pragma unroll
  for (int q = 0; q < 4; ++q)
    *(uint4*)(base + q * 256) = ((const uint4*)hi)[q];
}

// ---- fused: A-convert+stage, barrier-free MFMA argmin, loss, hist, z_q gather
// v2: 64-row blocks (32 KB LDS, 3 blocks/CU), per-wave COLUMN split (B read once
// per block), full-line z_q writes.
__global__ __launch_bounds__(256, 3) void argmin_kernel(
    const float* __restrict__ z, const float* __restrict__ ew,
    const char* __restrict__ bpk, const float* __restrict__ enorm64,
    float* __restrict__ out, float* __restrict__ out_idx,
    float* __restrict__ loss_acc, int* __restrict__ hist,
    int* __restrict__ flagcnt, int* __restrict__ flags) {
  __shared__ __align__(16) char As[32768];   // [chunk(rg*8+kc)][lane] fp16 frags, 64 rows
  __shared__ float red[4];

  const int t = threadIdx.x, lane = t & 63, w = t >> 6;
  const int quad = lane >> 4, l15 = lane & 15;
  const int rb = blockIdx.x * 64;

  // ---- stage A: fp32 -> fp16 frag layout in LDS; fused ||z||^2 partial
  float zsum = 0.f;
#pragma unroll
  for (int i = 0; i < 8; ++i) {
    const int slot = i * 256 + t;
    const int chunk = slot >> 6, ln = slot & 63;
    const int rg = chunk >> 3, kc = chunk & 7;
    const int row = rb + rg * 16 + (ln & 15);
    const float* src = z + (size_t)row * D + kc * 32 + (ln >> 4) * 8;
    const float4 f0 = *(const float4*)src;
    const float4 f1 = *(const float4*)(src + 4);
    zsum += f0.x*f0.x + f0.y*f0.y + f0.z*f0.z + f0.w*f0.w
          + f1.x*f1.x + f1.y*f1.y + f1.z*f1.z + f1.w*f1.w;
    _Float16 hb[8] = {(_Float16)f0.x, (_Float16)f0.y, (_Float16)f0.z, (_Float16)f0.w,
                      (_Float16)f1.x, (_Float16)f1.y, (_Float16)f1.z, (_Float16)f1.w};
    *(uint4*)(As + slot * 16) = *(const uint4*)hb;
  }
  __syncthreads();

  int min1[16], min2[16];
#pragma unroll
  for (int s = 0; s < 16; ++s) { min1[s] = 0x7FFFFFFF; min2[s] = 0x7FFFFFFF; }

  // ---- main loop: ZERO barriers. Wave w owns cols [w*512, w*512+512).
  // Per nt: 64 cols (4 ct), all 64 rows (4 rt).
#pragma unroll 1
  for (int nt = 0; nt < 8; ++nt) {
    float en[4];
#pragma unroll
    for (int ct = 0; ct < 4; ++ct)
      en[ct] = enorm64[w * 512 + nt * 64 + ct * 16 + l15];

    floatx4 acc[4][4];
#pragma unroll
    for (int rt = 0; rt < 4; ++rt)
#pragma unroll
      for (int ct = 0; ct < 4; ++ct) acc[rt][ct] = 0;

    const char* bnt = bpk + (((size_t)(w * 32 + nt * 4) * 8) << 10) + lane * 16;
#pragma unroll 2
    for (int kc = 0; kc < 8; ++kc) {
      half8 a[4], b[4];
#pragma unroll
      for (int rt = 0; rt < 4; ++rt)
        a[rt] = *(const half8*)(As + ((rt * 8 + kc) << 10) + lane * 16);
#pragma unroll
      for (int ct = 0; ct < 4; ++ct)
        b[ct] = *(const half8*)(bnt + ct * 8192 + (kc << 10));
#pragma unroll
      for (int rt = 0; rt < 4; ++rt)
#pragma unroll
        for (int ct = 0; ct < 4; ++ct)
          acc[rt][ct] = __builtin_amdgcn_mfma_f32_16x16x32_f16(a[rt], b[ct], acc[rt][ct], 0, 0, 0);
    }

    // epilogue: quantized integer keys, min1/min2 per row-slot
#pragma unroll
    for (int ct = 0; ct < 4; ++ct) {
      const int cg = w * 512 + nt * 64 + ct * 16 + l15;
#pragma unroll
      for (int rt = 0; rt < 4; ++rt)
#pragma unroll
        for (int r = 0; r < 4; ++r) {
          const int q = (int)fmaf(-128.0f, acc[rt][ct][r], en[ct]);  // trunc(64*dist)
          const int key = q * 2048 + cg;
          const int s = rt * 4 + r;
          min2[s] = min(min2[s], max(key, min1[s]));
          min1[s] = min(min1[s], key);
        }
    }
  }

  // ---- merge: 16 lanes of same row, then across the 4 waves via LDS
#pragma unroll
  for (int s = 0; s < 16; ++s) {
    int m1 = min1[s], m2 = min2[s];
#pragma unroll
    for (int m = 1; m < 16; m <<= 1) {
      const int o1 = __shfl_xor(m1, m, 64);
      const int o2 = __shfl_xor(m2, m, 64);
      m2 = min(min(m2, o2), max(m1, o1));
      m1 = min(m1, o1);
    }
    min1[s] = m1; min2[s] = m2;
  }
  __syncthreads();                       // As now reusable as scratch
  int* lm1 = (int*)As;                   // [w][64]
  int* lm2 = lm1 + 256;
  int* lidx = lm2 + 256;                 // [64]
#pragma unroll
  for (int s = 0; s < 16; ++s) {
    if (l15 == 0) {
      const int rowl = (s >> 2) * 16 + quad * 4 + (s & 3);
      lm1[w * 64 + rowl] = min1[s];
      lm2[w * 64 + rowl] = min2[s];
    }
  }
  __syncthreads();

  int qbest = 0;
  if (t < 64) {
    const int a1 = lm1[t],       a2 = lm2[t];
    const int b1 = lm1[64 + t],  b2 = lm2[64 + t];
    const int c1 = lm1[128 + t], c2 = lm2[128 + t];
    const int d1 = lm1[192 + t], d2 = lm2[192 + t];
    const int mab = min(a1, b1), sab = min(max(a1, b1), min(a2, b2));
    const int mcd = min(c1, d1), scd = min(max(c1, d1), min(c2, d2));
    const int m1 = min(mab, mcd);
    const int m2 = min(min(sab, scd), max(mab, mcd));
    const int idxv = m1 & 2047;
    out_idx[rb + t] = (float)idxv;
    lidx[t] = idxv;
    qbest = (m1 >> 11);
    atomicAdd(&hist[idxv], 1);
    if ((m2 >> 11) - (m1 >> 11) < FLAG_Q) {
      const int p = atomicAdd(flagcnt, 1);
      flags[p] = rb + t;
    }
  }
  __syncthreads();

  // ---- z_q write: ONE ROW PER WAVE-INSTRUCTION (64 lanes x 16 B = 1 KB = full row)
  for (int r = 0; r < 16; ++r) {
    const int rowl = w * 16 + r;
    const int idx = lidx[rowl];
    const float4 v = ((const float4*)(ew + (size_t)idx * D))[lane];
    ((float4*)(out + ((size_t)rb + rowl) * D))[lane] = v;
  }

  // ---- loss: sum(best_dist) + sum(||z||^2), block-reduced
  float lv = zsum + (float)qbest * (1.0f / 64.0f);
#pragma unroll
  for (int off = 32; off > 0; off >>= 1) lv += __shfl_down(lv, off, 64);
  if (lane == 0) red[w] = lv;
  __syncthreads();
  if (t == 0) atomicAdd(loss_acc, red[0] + red[1] + red[2] + red[3]);
}

// ---- exact fp32 rescue: fix idx, hist, z_q for near-tie rows
__global__ __launch_bounds__(256) void rescue_kernel(const float* __restrict__ z,
                                                     const float* __restrict__ ew,
                                                     const float* __restrict__ enorm,
                                                     const int* __restrict__ flagcnt,
                                                     const int* __restrict__ flags,
                                                     float* __restrict__ out_idx,
                                                     float* __restrict__ out,
                                                     int* __restrict__ hist) {
  __shared__ __align__(16) float zs[8][256];
  __shared__ unsigned long long bkey[8];
  __shared__ int rrow[8], ridx[8], rchg[8];
  const int t = threadIdx.x;
  const int cnt = flagcnt[0];
  for (int grp = blockIdx.x; grp * 8 < cnt; grp += gridDim.x) {
    const int nr = min(8, cnt - grp * 8);
    __syncthreads();
    {
      const int rr = t >> 5, d8 = t & 31;
      if (rr < nr) {
        const int row = flags[grp * 8 + rr];
        if (d8 == 0) rrow[rr] = row;
        const float4* s = (const float4*)(z + (size_t)row * D + d8 * 8);
        *(float4*)&zs[rr][d8 * 8]     = s[0];
        *(float4*)&zs[rr][d8 * 8 + 4] = s[1];
      }
    }
    if (t < 8) bkey[t] = ~0ULL;
    __syncthreads();

    unsigned long long mykey[8];
#pragma unroll
    for (int rr = 0; rr < 8; ++rr) mykey[rr] = ~0ULL;

    for (int cc = 0; cc < 8; ++cc) {
      const int c = cc * 256 + t;
      float acc[8];
#pragma unroll
      for (int rr = 0; rr < 8; ++rr) acc[rr] = 0.f;
      const float4* ev = (const float4*)(ew + (size_t)c * D);
#pragma unroll 2
      for (int d4 = 0; d4 < 64; ++d4) {
        const float4 e = ev[d4];
#pragma unroll
        for (int rr = 0; rr < 8; ++rr) {
          const float4 zz = *(const float4*)&zs[rr][d4 * 4];
          float a = acc[rr];
          a = fmaf(e.x, zz.x, a); a = fmaf(e.y, zz.y, a);
          a = fmaf(e.z, zz.z, a); a = fmaf(e.w, zz.w, a);
          acc[rr] = a;
        }
      }
      const float en = enorm[c];
#pragma unroll
      for (int rr = 0; rr < 8; ++rr) {
        const float dv = fmaf(-2.0f, acc[rr], en);
        const unsigned b = __float_as_uint(dv);
        const unsigned k32 = b ^ ((unsigned)((int)b >> 31) | 0x80000000u);
        const unsigned long long key = ((unsigned long long)k32 << 32) | (unsigned)c;
        if (key < mykey[rr]) mykey[rr] = key;
      }
    }
#pragma unroll
    for (int rr = 0; rr < 8; ++rr)
      if (rr < nr) atomicMin(&bkey[rr], mykey[rr]);
    __syncthreads();
    if (t < nr) {
      const int row = rrow[t];
      const int newidx = (int)(unsigned)(bkey[t] & 0xFFFFFFFFu);
      const int oldidx = (int)out_idx[row];
      ridx[t] = newidx;
      rchg[t] = (newidx != oldidx);
      if (newidx != oldidx) {
        atomicSub(&hist[oldidx], 1);
        atomicAdd(&hist[newidx], 1);
        out_idx[row] = (float)newidx;
      }
    }
    __syncthreads();
    {
      const int rr = t >> 5, c8 = (t & 31) * 2;
      if (rr < nr && rchg[rr]) {
        const int row = rrow[rr], idx = ridx[rr];
        const float4* src = (const float4*)(ew + (size_t)idx * D) + c8;
        float4* dst = (float4*)(out + (size_t)row * D) + c8;
        dst[0] = src[0]; dst[1] = src[1];
      }
    }
  }
}

// ---- loss + perplexity
__global__ __launch_bounds__(256) void finalize_kernel(const int* __restrict__ hist,
                                                       const float* __restrict__ loss_acc,
                                                       float* __restrict__ out) {
  __shared__ float red[256];
  const int t = threadIdx.x;
  float local = 0.f;
  for (int k = t; k < K; k += 256) {
    const float p = (float)hist[k] * (1.0f / (float)N_ROWS);
    local += p * logf(p + 1e-10f);
  }
  red[t] = local;
  __syncthreads();
  for (int s = 128; s > 0; s >>= 1) {
    if (t < s) red[t] += red[t + s];
    __syncthreads();
  }
  if (t == 0) {
    out[LOSS_OFF] = 0.25f * loss_acc[0] * (1.0f / (float)((size_t)N_ROWS * D));
    out[PERP_OFF] = expf(-red[0]);
  }
}

extern "C" void kernel_launch(void* const* d_in, const int* in_sizes, int n_in,
                              void* d_out, int out_size, void* d_ws, size_t ws_size,
                              hipStream_t stream) {
  const float* z  = (const float*)d_in[0];
  const float* ew = (const float*)d_in[1];
  float* out = (float*)d_out;

  char* ws = (char*)d_ws;
  int*   hist     = (int*)(ws + WS_HIST);
  float* loss_acc = (float*)(ws + WS_LOSS);
  int*   flagcnt  = (int*)(ws + WS_FLAGCNT);
  float* enorm    = (float*)(ws + WS_ENORM);
  float* enorm64  = (float*)(ws + WS_ENORM64);
  int*   flags    = (int*)(ws + WS_FLAGS);
  char*  bpk      = ws + WS_BPK;

  convertB_kernel<<<64, 256, 0, stream>>>(ew, bpk, enorm, enorm64,
                                          hist, loss_acc, flagcnt);
  argmin_kernel<<<N_ROWS / 64, 256, 0, stream>>>(z, ew, bpk, enorm64,
                                                 out, out + IDX_OFF, loss_acc,
                                                 hist, flagcnt, flags);
  rescue_kernel<<<512, 256, 0, stream>>>(z, ew, enorm, flagcnt, flags,
                                         out + IDX_OFF, out, hist);
  finalize_kernel<<<1, 256, 0, stream>>>(hist, loss_acc, out);
}

// Round 2
// 281.645 us; speedup vs baseline: 1.4630x; 1.4014x over previous
//
#include <hip/hip_runtime.h>
#include <math.h>

#define N_ROWS 65536
#define D 256
#define K 2048

// d_out float layout: z_q_st | loss | indices | perplexity
#define LOSS_OFF 16777216L
#define IDX_OFF  16777217L
#define PERP_OFF 16842753L

// ws byte layout
#define WS_HIST    0           // 2048*4
#define WS_LOSS    8192
#define WS_FLAGCNT 8196
#define WS_TICKET  8200        // rescue dynamic group counter
#define WS_ENORM   8448        // 2048*4 (exact fp32, rescue)
#define WS_ENORM64 16640       // 2048*4 (64*enorm, argmin epilogue)
#define WS_FLAGS   24832       // 65536*4
#define WS_BPK     287232      // 1 MB frag-packed B
#define WS_EWT     1335808     // 2 MB fp32 transposed ew [256][2048]

#define FLAG_Q 12              // quantized-gap threshold (12/64 = 0.1875)

typedef _Float16 half8 __attribute__((ext_vector_type(8)));
typedef float floatx4 __attribute__((ext_vector_type(4)));

// ---- convert B: ew fp32 -> fp16 frag-packed bpk + fp32 transposed ewT
//      + enorm/enorm64 + zero accumulators
__global__ __launch_bounds__(256) void convertB_kernel(const float* __restrict__ ew,
                                                       char* __restrict__ bpk,
                                                       float* __restrict__ ewT,
                                                       float* __restrict__ enorm,
                                                       float* __restrict__ enorm64,
                                                       int* __restrict__ hist,
                                                       float* __restrict__ loss_acc,
                                                       int* __restrict__ flagcnt,
                                                       int* __restrict__ ticket) {
  const int gid = blockIdx.x * 256 + threadIdx.x;   // 16384
  if (gid < 2048) hist[gid] = 0;
  else if (gid == 2048) *loss_acc = 0.f;
  else if (gid == 2049) *flagcnt = 0;
  else if (gid == 2050) *ticket = 0;

  const int code = gid >> 3, kc = gid & 7;
  const float4* s4 = (const float4*)(ew + (size_t)code * D + kc * 32);
  float buf[32];
#pragma unroll
  for (int q = 0; q < 8; ++q) *(float4*)&buf[q * 4] = s4[q];
  float s = 0.f;
#pragma unroll
  for (int k = 0; k < 32; ++k) s = fmaf(buf[k], buf[k], s);
  s += __shfl_xor(s, 1, 64); s += __shfl_xor(s, 2, 64); s += __shfl_xor(s, 4, 64);
  if (kc == 0) { enorm[code] = s; enorm64[code] = s * 64.0f; }

  // fp32 transposed copy for rescue (coalesced column reads there)
  {
    float* col = ewT + code;
#pragma unroll
    for (int k = 0; k < 32; ++k) col[(size_t)(kc * 32 + k) * K] = buf[k];
  }

  _Float16 hi[32];
#pragma unroll
  for (int k = 0; k < 32; ++k) hi[k] = (_Float16)buf[k];
  // chunk = (code>>4)*8 + kc ; within chunk lane = (code&15) + 16*q holds halfs q*8..q*8+7
  char* base = bpk + (((size_t)(code >> 4) * 8 + kc) << 10) + (code & 15) * 16;
#pragma unroll
  for (int q = 0; q < 4; ++q)
    *(uint4*)(base + q * 256) = ((const uint4*)hi)[q];
}

// ---- fused: A-convert+stage, barrier-free MFMA argmin, loss, hist, z_q gather
// v2: 64-row blocks (32 KB LDS, 3 blocks/CU), per-wave COLUMN split (B read once
// per block), full-line z_q writes.
__global__ __launch_bounds__(256, 3) void argmin_kernel(
    const float* __restrict__ z, const float* __restrict__ ew,
    const char* __restrict__ bpk, const float* __restrict__ enorm64,
    float* __restrict__ out, float* __restrict__ out_idx,
    float* __restrict__ loss_acc, int* __restrict__ hist,
    int* __restrict__ flagcnt, int* __restrict__ flags) {
  __shared__ __align__(16) char As[32768];   // [chunk(rg*8+kc)][lane] fp16 frags, 64 rows
  __shared__ float red[4];

  const int t = threadIdx.x, lane = t & 63, w = t >> 6;
  const int quad = lane >> 4, l15 = lane & 15;
  const int rb = blockIdx.x * 64;

  // ---- stage A: fp32 -> fp16 frag layout in LDS; fused ||z||^2 partial
  float zsum = 0.f;
#pragma unroll
  for (int i = 0; i < 8; ++i) {
    const int slot = i * 256 + t;
    const int chunk = slot >> 6, ln = slot & 63;
    const int rg = chunk >> 3, kc = chunk & 7;
    const int row = rb + rg * 16 + (ln & 15);
    const float* src = z + (size_t)row * D + kc * 32 + (ln >> 4) * 8;
    const float4 f0 = *(const float4*)src;
    const float4 f1 = *(const float4*)(src + 4);
    zsum += f0.x*f0.x + f0.y*f0.y + f0.z*f0.z + f0.w*f0.w
          + f1.x*f1.x + f1.y*f1.y + f1.z*f1.z + f1.w*f1.w;
    _Float16 hb[8] = {(_Float16)f0.x, (_Float16)f0.y, (_Float16)f0.z, (_Float16)f0.w,
                      (_Float16)f1.x, (_Float16)f1.y, (_Float16)f1.z, (_Float16)f1.w};
    *(uint4*)(As + slot * 16) = *(const uint4*)hb;
  }
  __syncthreads();

  int min1[16], min2[16];
#pragma unroll
  for (int s = 0; s < 16; ++s) { min1[s] = 0x7FFFFFFF; min2[s] = 0x7FFFFFFF; }

  // ---- main loop: ZERO barriers. Wave w owns cols [w*512, w*512+512).
  // Per nt: 64 cols (4 ct), all 64 rows (4 rt).
#pragma unroll 1
  for (int nt = 0; nt < 8; ++nt) {
    float en[4];
#pragma unroll
    for (int ct = 0; ct < 4; ++ct)
      en[ct] = enorm64[w * 512 + nt * 64 + ct * 16 + l15];

    floatx4 acc[4][4];
#pragma unroll
    for (int rt = 0; rt < 4; ++rt)
#pragma unroll
      for (int ct = 0; ct < 4; ++ct) acc[rt][ct] = 0;

    const char* bnt = bpk + (((size_t)(w * 32 + nt * 4) * 8) << 10) + lane * 16;
#pragma unroll 2
    for (int kc = 0; kc < 8; ++kc) {
      half8 a[4], b[4];
#pragma unroll
      for (int rt = 0; rt < 4; ++rt)
        a[rt] = *(const half8*)(As + ((rt * 8 + kc) << 10) + lane * 16);
#pragma unroll
      for (int ct = 0; ct < 4; ++ct)
        b[ct] = *(const half8*)(bnt + ct * 8192 + (kc << 10));
#pragma unroll
      for (int rt = 0; rt < 4; ++rt)
#pragma unroll
        for (int ct = 0; ct < 4; ++ct)
          acc[rt][ct] = __builtin_amdgcn_mfma_f32_16x16x32_f16(a[rt], b[ct], acc[rt][ct], 0, 0, 0);
    }

    // epilogue: quantized integer keys, min1/min2 per row-slot
#pragma unroll
    for (int ct = 0; ct < 4; ++ct) {
      const int cg = w * 512 + nt * 64 + ct * 16 + l15;
#pragma unroll
      for (int rt = 0; rt < 4; ++rt)
#pragma unroll
        for (int r = 0; r < 4; ++r) {
          const int q = (int)fmaf(-128.0f, acc[rt][ct][r], en[ct]);  // trunc(64*dist)
          const int key = q * 2048 + cg;
          const int s = rt * 4 + r;
          min2[s] = min(min2[s], max(key, min1[s]));
          min1[s] = min(min1[s], key);
        }
    }
  }

  // ---- merge: 16 lanes of same row, then across the 4 waves via LDS
#pragma unroll
  for (int s = 0; s < 16; ++s) {
    int m1 = min1[s], m2 = min2[s];
#pragma unroll
    for (int m = 1; m < 16; m <<= 1) {
      const int o1 = __shfl_xor(m1, m, 64);
      const int o2 = __shfl_xor(m2, m, 64);
      m2 = min(min(m2, o2), max(m1, o1));
      m1 = min(m1, o1);
    }
    min1[s] = m1; min2[s] = m2;
  }
  __syncthreads();                       // As now reusable as scratch
  int* lm1 = (int*)As;                   // [w][64]
  int* lm2 = lm1 + 256;
  int* lidx = lm2 + 256;                 // [64]
#pragma unroll
  for (int s = 0; s < 16; ++s) {
    if (l15 == 0) {
      const int rowl = (s >> 2) * 16 + quad * 4 + (s & 3);
      lm1[w * 64 + rowl] = min1[s];
      lm2[w * 64 + rowl] = min2[s];
    }
  }
  __syncthreads();

  int qbest = 0;
  if (t < 64) {
    const int a1 = lm1[t],       a2 = lm2[t];
    const int b1 = lm1[64 + t],  b2 = lm2[64 + t];
    const int c1 = lm1[128 + t], c2 = lm2[128 + t];
    const int d1 = lm1[192 + t], d2 = lm2[192 + t];
    const int mab = min(a1, b1), sab = min(max(a1, b1), min(a2, b2));
    const int mcd = min(c1, d1), scd = min(max(c1, d1), min(c2, d2));
    const int m1 = min(mab, mcd);
    const int m2 = min(min(sab, scd), max(mab, mcd));
    const int idxv = m1 & 2047;
    out_idx[rb + t] = (float)idxv;
    lidx[t] = idxv;
    qbest = (m1 >> 11);
    atomicAdd(&hist[idxv], 1);
    if ((m2 >> 11) - (m1 >> 11) < FLAG_Q) {
      const int p = atomicAdd(flagcnt, 1);
      flags[p] = rb + t;
    }
  }
  __syncthreads();

  // ---- z_q write: ONE ROW PER WAVE-INSTRUCTION (64 lanes x 16 B = 1 KB = full row)
  for (int r = 0; r < 16; ++r) {
    const int rowl = w * 16 + r;
    const int idx = lidx[rowl];
    const float4 v = ((const float4*)(ew + (size_t)idx * D))[lane];
    ((float4*)(out + ((size_t)rb + rowl) * D))[lane] = v;
  }

  // ---- loss: sum(best_dist) + sum(||z||^2), block-reduced
  float lv = zsum + (float)qbest * (1.0f / 64.0f);
#pragma unroll
  for (int off = 32; off > 0; off >>= 1) lv += __shfl_down(lv, off, 64);
  if (lane == 0) red[w] = lv;
  __syncthreads();
  if (t == 0) atomicAdd(loss_acc, red[0] + red[1] + red[2] + red[3]);
}

// ---- exact fp32 rescue v2: transposed ewT (coalesced), 512 threads, 4 cols/thread,
//      dynamic ticket. Fixes idx, hist, z_q for near-tie rows.
__global__ __launch_bounds__(512) void rescue_kernel(
    const float* __restrict__ z, const float* __restrict__ ew,
    const float* __restrict__ ewT, const float* __restrict__ enorm,
    const int* __restrict__ flagcnt, const int* __restrict__ flags,
    int* __restrict__ ticket,
    float* __restrict__ out_idx, float* __restrict__ out,
    int* __restrict__ hist) {
  __shared__ __align__(16) float zsT[256 * 8];   // [d][r] transposed rows
  __shared__ unsigned long long bkey[8];
  __shared__ int rrow[8], ridx[8], rchg[8], grpS;
  const int t = threadIdx.x, lane = t & 63, rr = t >> 6;
  const int cnt = flagcnt[0];
  const float4 en4 = ((const float4*)enorm)[t];   // cols 4t..4t+3

  for (;;) {
    if (t == 0) grpS = atomicAdd(ticket, 1);
    __syncthreads();                // publishes grpS; guards zsT/bkey reuse
    const int grp = grpS;
    if (grp * 8 >= cnt) break;
    const int nr = min(8, cnt - grp * 8);

    if (rr < nr) {
      const int row = flags[grp * 8 + rr];
      if (lane == 0) rrow[rr] = row;
      const float4 v = ((const float4*)(z + (size_t)row * D))[lane];
      zsT[(lane * 4 + 0) * 8 + rr] = v.x;
      zsT[(lane * 4 + 1) * 8 + rr] = v.y;
      zsT[(lane * 4 + 2) * 8 + rr] = v.z;
      zsT[(lane * 4 + 3) * 8 + rr] = v.w;
    }
    if (t < 8) bkey[t] = ~0ULL;
    __syncthreads();

    float acc[8][4];
#pragma unroll
    for (int r = 0; r < 8; ++r)
#pragma unroll
      for (int c = 0; c < 4; ++c) acc[r][c] = 0.f;

    const float4* ecol = (const float4*)ewT + t;   // ewT[d][4t..4t+3]
#pragma unroll 4
    for (int d = 0; d < 256; ++d) {
      const float4 e = ecol[(size_t)d * 512];
      const float4 za = *(const float4*)&zsT[d * 8];       // broadcast
      const float4 zb = *(const float4*)&zsT[d * 8 + 4];   // broadcast
      const float zr[8] = {za.x, za.y, za.z, za.w, zb.x, zb.y, zb.z, zb.w};
      const float ec[4] = {e.x, e.y, e.z, e.w};
#pragma unroll
      for (int r = 0; r < 8; ++r)
#pragma unroll
        for (int c = 0; c < 4; ++c)
          acc[r][c] = fmaf(ec[c], zr[r], acc[r][c]);
    }

    const float enc[4] = {en4.x, en4.y, en4.z, en4.w};
    unsigned long long mykey[8];
#pragma unroll
    for (int r = 0; r < 8; ++r) {
      unsigned long long best = ~0ULL;
#pragma unroll
      for (int c = 0; c < 4; ++c) {
        const float dv = fmaf(-2.0f, acc[r][c], enc[c]);
        const unsigned b = __float_as_uint(dv);
        const unsigned k32 = b ^ ((unsigned)((int)b >> 31) | 0x80000000u);
        const unsigned long long key =
            ((unsigned long long)k32 << 32) | (unsigned)(4 * t + c);
        best = min(best, key);
      }
      mykey[r] = best;
    }
    // wave butterfly reduce, then one atomicMin per wave per row
#pragma unroll
    for (int m = 1; m < 64; m <<= 1)
#pragma unroll
      for (int r = 0; r < 8; ++r) {
        const unsigned long long o = __shfl_xor(mykey[r], m, 64);
        mykey[r] = min(mykey[r], o);
      }
    if (lane == 0) {
#pragma unroll
      for (int r = 0; r < 8; ++r)
        if (r < nr) atomicMin(&bkey[r], mykey[r]);
    }
    __syncthreads();

    if (t < nr) {
      const int row = rrow[t];
      const int newidx = (int)(unsigned)(bkey[t] & 0xFFFFFFFFu);
      const int oldidx = (int)out_idx[row];
      ridx[t] = newidx;
      rchg[t] = (newidx != oldidx);
      if (newidx != oldidx) {
        atomicSub(&hist[oldidx], 1);
        atomicAdd(&hist[newidx], 1);
        out_idx[row] = (float)newidx;
      }
    }
    __syncthreads();
    if (rr < nr && rchg[rr]) {
      const int row = rrow[rr], idx = ridx[rr];
      ((float4*)(out + (size_t)row * D))[lane] =
          ((const float4*)(ew + (size_t)idx * D))[lane];
    }
  }
}

// ---- loss + perplexity
__global__ __launch_bounds__(256) void finalize_kernel(const int* __restrict__ hist,
                                                       const float* __restrict__ loss_acc,
                                                       float* __restrict__ out) {
  __shared__ float red[256];
  const int t = threadIdx.x;
  float local = 0.f;
  for (int k = t; k < K; k += 256) {
    const float p = (float)hist[k] * (1.0f / (float)N_ROWS);
    local += p * logf(p + 1e-10f);
  }
  red[t] = local;
  __syncthreads();
  for (int s = 128; s > 0; s >>= 1) {
    if (t < s) red[t] += red[t + s];
    __syncthreads();
  }
  if (t == 0) {
    out[LOSS_OFF] = 0.25f * loss_acc[0] * (1.0f / (float)((size_t)N_ROWS * D));
    out[PERP_OFF] = expf(-red[0]);
  }
}

extern "C" void kernel_launch(void* const* d_in, const int* in_sizes, int n_in,
                              void* d_out, int out_size, void* d_ws, size_t ws_size,
                              hipStream_t stream) {
  const float* z  = (const float*)d_in[0];
  const float* ew = (const float*)d_in[1];
  float* out = (float*)d_out;

  char* ws = (char*)d_ws;
  int*   hist     = (int*)(ws + WS_HIST);
  float* loss_acc = (float*)(ws + WS_LOSS);
  int*   flagcnt  = (int*)(ws + WS_FLAGCNT);
  int*   ticket   = (int*)(ws + WS_TICKET);
  float* enorm    = (float*)(ws + WS_ENORM);
  float* enorm64  = (float*)(ws + WS_ENORM64);
  int*   flags    = (int*)(ws + WS_FLAGS);
  char*  bpk      = ws + WS_BPK;
  float* ewT      = (float*)(ws + WS_EWT);

  convertB_kernel<<<64, 256, 0, stream>>>(ew, bpk, ewT, enorm, enorm64,
                                          hist, loss_acc, flagcnt, ticket);
  argmin_kernel<<<N_ROWS / 64, 256, 0, stream>>>(z, ew, bpk, enorm64,
                                                 out, out + IDX_OFF, loss_acc,
                                                 hist, flagcnt, flags);
  rescue_kernel<<<512, 512, 0, stream>>>(z, ew, ewT, enorm, flagcnt, flags,
                                         ticket, out + IDX_OFF, out, hist);
  finalize_kernel<<<1, 256, 0, stream>>>(hist, loss_acc, out);
}